// Round 1
// baseline (139.373 us; speedup 1.0000x reference)
//
#include <hip/hip_runtime.h>

#define B_ 8
#define C_ 512
#define D_ 128

typedef __bf16 v8bf __attribute__((ext_vector_type(8)));
typedef float v4f __attribute__((ext_vector_type(4)));
typedef float fvec4 __attribute__((ext_vector_type(4)));
typedef unsigned short u16;
typedef u16 u16x4 __attribute__((ext_vector_type(4)));
typedef u16 u16x8 __attribute__((ext_vector_type(8)));

// f32 -> bf16 round-to-nearest-even
__device__ __forceinline__ u16 f2bf(float f) {
  unsigned u = __builtin_bit_cast(unsigned, f);
  u = u + 0x7FFFu + ((u >> 16) & 1u);
  return (u16)(u >> 16);
}

// Stage a 32x128 f32 K-chunk transposed into LDS kt[128][40] (bf16).
// Thread t reads K[c][d] for 4 c's (coalesced in d across lanes), writes b64.
__device__ __forceinline__ void stage_kt(const float* __restrict__ Kbase,
                                         u16* kt, int tid) {
  const int d = tid & 127;
  const int c0 = (tid >> 7) * 4;
#pragma unroll
  for (int p = 0; p < 4; ++p) {
    const int c = c0 + 8 * p;
    u16x4 u;
#pragma unroll
    for (int i = 0; i < 4; ++i)
      u[i] = f2bf(Kbase[(size_t)(c + i) * D_ + d]);
    *(u16x4*)&kt[d * 40 + c] = u;
  }
}

// ---------------- Kernel 1: projected queries ----------------
// grid: (16 row-tiles, 8 batches), 256 threads (4 waves).
// Per block: rows [t*32, t*32+32) of batch b.
__global__ __launch_bounds__(256) void k_proj(
    const float* __restrict__ Q, const float* __restrict__ K,
    const float* __restrict__ carry, float* __restrict__ out) {
  const int t = blockIdx.x;
  const int b = blockIdx.y;
  const int tid = threadIdx.x;
  const int w = tid >> 6;
  const int l = tid & 63;
  const int lr = l & 15;
  const int lg = l >> 4;
  const int wr = (w & 1) * 16;   // wave's row offset in 32-row tile
  const int wc = (w >> 1) * 64;  // wave's col offset in D
  const int r0 = t * 32;

  __shared__ u16 ks[32 * 136];   // row-major K chunk (S-step B operand)
  __shared__ u16 kt[128 * 40];   // transposed K chunk (PV-step B operand)
  __shared__ u16 sl[32 * 40];    // masked S chunk (bf16)

  // --- Q A-fragments: rows r0+wr+lr, k = kk*32 + lg*8 + e. Reused all chunks.
  v8bf qf[4];
  {
    const float* qrow = Q + (size_t)(b * C_ + r0 + wr + lr) * D_;
#pragma unroll
    for (int kk = 0; kk < 4; ++kk) {
      const float* p = qrow + kk * 32 + lg * 8;
      fvec4 a = *(const fvec4*)p;
      fvec4 c = *(const fvec4*)(p + 4);
      u16x8 u;
      u[0] = f2bf(a[0]); u[1] = f2bf(a[1]); u[2] = f2bf(a[2]); u[3] = f2bf(a[3]);
      u[4] = f2bf(c[0]); u[5] = f2bf(c[1]); u[6] = f2bf(c[2]); u[7] = f2bf(c[3]);
      qf[kk] = __builtin_bit_cast(v8bf, u);
    }
  }

  // --- init O with carry term: O[r][i] = sum_j Q[r][j] * carry[i][j]
  v4f acc[4] = {{0.f, 0.f, 0.f, 0.f}, {0.f, 0.f, 0.f, 0.f},
                {0.f, 0.f, 0.f, 0.f}, {0.f, 0.f, 0.f, 0.f}};
#pragma unroll
  for (int kk = 0; kk < 4; ++kk) {
#pragma unroll
    for (int n = 0; n < 4; ++n) {
      const int icol = wc + n * 16 + lr;
      const float* p = carry + (size_t)icol * D_ + kk * 32 + lg * 8;
      fvec4 a = *(const fvec4*)p;
      fvec4 c = *(const fvec4*)(p + 4);
      u16x8 u;
      u[0] = f2bf(a[0]); u[1] = f2bf(a[1]); u[2] = f2bf(a[2]); u[3] = f2bf(a[3]);
      u[4] = f2bf(c[0]); u[5] = f2bf(c[1]); u[6] = f2bf(c[2]); u[7] = f2bf(c[3]);
      acc[n] = __builtin_amdgcn_mfma_f32_16x16x32_bf16(
          qf[kk], __builtin_bit_cast(v8bf, u), acc[n], 0, 0, 0);
    }
  }

  // --- causal chunk loop over K chunks 0..t
  for (int cc = 0; cc <= t; ++cc) {
    const int base = cc * 32;
    const float* Kbase = K + (size_t)(b * C_ + base) * D_;
    __syncthreads();
    // stage ks (row-major): thread reads K[row][d0..d0+3] coalesced
    {
      int row = tid >> 5;
      const int d0 = (tid & 31) * 4;
#pragma unroll
      for (int p = 0; p < 4; ++p, row += 8) {
        fvec4 v = *(const fvec4*)(Kbase + (size_t)row * D_ + d0);
        u16x4 u;
        u[0] = f2bf(v[0]); u[1] = f2bf(v[1]); u[2] = f2bf(v[2]); u[3] = f2bf(v[3]);
        *(u16x4*)&ks[row * 136 + d0] = u;
      }
    }
    stage_kt(Kbase, kt, tid);
    __syncthreads();

    // S tile = Q * Kchunk^T : wave computes S[wr..wr+16][sc0..sc0+16]
    const int sc0 = (w >> 1) * 16;
    v4f sacc = {0.f, 0.f, 0.f, 0.f};
#pragma unroll
    for (int kk = 0; kk < 4; ++kk) {
      v8bf bf = *(const v8bf*)&ks[(sc0 + lr) * 136 + kk * 32 + lg * 8];
      sacc = __builtin_amdgcn_mfma_f32_16x16x32_bf16(qf[kk], bf, sacc, 0, 0, 0);
    }
    // masked bf16 write of S to LDS (causal: keep c' <= r)
    const bool diag = (cc == t);
#pragma unroll
    for (int j = 0; j < 4; ++j) {
      const int sr = wr + lg * 4 + j;  // row in 32-row tile
      const int sc = sc0 + lr;         // col in 32-col chunk
      float v = sacc[j];
      if (diag && sc > sr) v = 0.f;
      sl[sr * 40 + sc] = f2bf(v);
    }
    __syncthreads();

    // PV: O += S * Kchunk  (A from sl, B from kt)
    v8bf af = *(const v8bf*)&sl[(wr + lr) * 40 + lg * 8];
#pragma unroll
    for (int n = 0; n < 4; ++n) {
      v8bf bf = *(const v8bf*)&kt[(wc + n * 16 + lr) * 40 + lg * 8];
      acc[n] = __builtin_amdgcn_mfma_f32_16x16x32_bf16(af, bf, acc[n], 0, 0, 0);
    }
  }

  // --- epilogue: C/D layout col = lane&15, row = 4*(lane>>4)+j
#pragma unroll
  for (int n = 0; n < 4; ++n)
#pragma unroll
    for (int j = 0; j < 4; ++j)
      out[(size_t)(b * C_ + r0 + wr + lg * 4 + j) * D_ + wc + n * 16 + lr] =
          acc[n][j];
}

// ---------------- Kernel 2: per-batch K^T K partials ----------------
__global__ __launch_bounds__(256) void k_syrk(const float* __restrict__ K,
                                              float* __restrict__ ws) {
  const int b = blockIdx.x;
  const int tid = threadIdx.x;
  const int w = tid >> 6;
  const int l = tid & 63;
  const int lr = l & 15;
  const int lg = l >> 4;

  __shared__ u16 kt[128 * 40];

  v4f acc[2][8];
#pragma unroll
  for (int mi = 0; mi < 2; ++mi)
#pragma unroll
    for (int n = 0; n < 8; ++n) acc[mi][n] = (v4f){0.f, 0.f, 0.f, 0.f};

  for (int cc = 0; cc < 16; ++cc) {
    __syncthreads();
    stage_kt(K + (size_t)(b * C_ + cc * 32) * D_, kt, tid);
    __syncthreads();
    v8bf fr[8];
#pragma unroll
    for (int x = 0; x < 8; ++x)
      fr[x] = *(const v8bf*)&kt[(x * 16 + lr) * 40 + lg * 8];
#pragma unroll
    for (int mi = 0; mi < 2; ++mi) {
      v8bf am = fr[2 * w + mi];
#pragma unroll
      for (int n = 0; n < 8; ++n)
        acc[mi][n] = __builtin_amdgcn_mfma_f32_16x16x32_bf16(am, fr[n],
                                                             acc[mi][n], 0, 0, 0);
    }
  }
#pragma unroll
  for (int mi = 0; mi < 2; ++mi)
#pragma unroll
    for (int n = 0; n < 8; ++n)
#pragma unroll
      for (int j = 0; j < 4; ++j)
        ws[(size_t)b * 16384 +
           (size_t)(16 * (2 * w + mi) + 4 * lg + j) * 128 + 16 * n + lr] =
            acc[mi][n][j];
}

// ---------------- Kernel 3: reduce partials + carry ----------------
__global__ __launch_bounds__(256) void k_reduce(const float* __restrict__ ws,
                                                const float* __restrict__ carry,
                                                float* __restrict__ out2) {
  const int i = blockIdx.x * 256 + threadIdx.x;
  float s = 0.f;
#pragma unroll
  for (int b = 0; b < B_; ++b) s += ws[(size_t)b * 16384 + i];
  out2[i] = carry[i] + 0.125f * s;
}

// ---------------- Fallback: single-block direct syrk (no ws) ----------------
__global__ __launch_bounds__(256) void k_syrk_direct(
    const float* __restrict__ K, const float* __restrict__ carry,
    float* __restrict__ out2) {
  const int tid = threadIdx.x;
  const int w = tid >> 6;
  const int l = tid & 63;
  const int lr = l & 15;
  const int lg = l >> 4;

  __shared__ u16 kt[128 * 40];

  v4f acc[2][8];
#pragma unroll
  for (int mi = 0; mi < 2; ++mi)
#pragma unroll
    for (int n = 0; n < 8; ++n) acc[mi][n] = (v4f){0.f, 0.f, 0.f, 0.f};

  for (int bb = 0; bb < B_; ++bb) {
    for (int cc = 0; cc < 16; ++cc) {
      __syncthreads();
      stage_kt(K + (size_t)(bb * C_ + cc * 32) * D_, kt, tid);
      __syncthreads();
      v8bf fr[8];
#pragma unroll
      for (int x = 0; x < 8; ++x)
        fr[x] = *(const v8bf*)&kt[(x * 16 + lr) * 40 + lg * 8];
#pragma unroll
      for (int mi = 0; mi < 2; ++mi) {
        v8bf am = fr[2 * w + mi];
#pragma unroll
        for (int n = 0; n < 8; ++n)
          acc[mi][n] = __builtin_amdgcn_mfma_f32_16x16x32_bf16(
              am, fr[n], acc[mi][n], 0, 0, 0);
      }
    }
  }
#pragma unroll
  for (int mi = 0; mi < 2; ++mi)
#pragma unroll
    for (int n = 0; n < 8; ++n)
#pragma unroll
      for (int j = 0; j < 4; ++j) {
        const int idx = (16 * (2 * w + mi) + 4 * lg + j) * 128 + 16 * n + lr;
        out2[idx] = carry[idx] + 0.125f * acc[mi][n][j];
      }
}

extern "C" void kernel_launch(void* const* d_in, const int* in_sizes, int n_in,
                              void* d_out, int out_size, void* d_ws,
                              size_t ws_size, hipStream_t stream) {
  const float* Q = (const float*)d_in[0];
  const float* K = (const float*)d_in[1];
  const float* carry = (const float*)d_in[2];
  float* out = (float*)d_out;
  float* out2 = out + (size_t)B_ * C_ * D_;

  k_proj<<<dim3(16, 8), 256, 0, stream>>>(Q, K, carry, out);

  if (ws_size >= (size_t)B_ * 16384 * sizeof(float)) {
    k_syrk<<<B_, 256, 0, stream>>>(K, (float*)d_ws);
    k_reduce<<<64, 256, 0, stream>>>((const float*)d_ws, carry, out2);
  } else {
    k_syrk_direct<<<1, 256, 0, stream>>>(K, carry, out2);
  }
}

// Round 2
// 40.173 us; speedup vs baseline: 3.4693x; 3.4693x over previous
//
#include <hip/hip_runtime.h>

#define B_ 8
#define C_ 512
#define D_ 128
#define LDK 136   // ks row stride (u16): 32x136, 2-way-free read/write banks
#define LDT 40    // kt row stride (u16): 16B-aligned b128 reads

typedef __bf16 v8bf __attribute__((ext_vector_type(8)));
typedef float v4f __attribute__((ext_vector_type(4)));
typedef float fvec4 __attribute__((ext_vector_type(4)));
typedef unsigned short u16;
typedef u16 u16x4 __attribute__((ext_vector_type(4)));

// f32 -> bf16 round-to-nearest-even
__device__ __forceinline__ u16 f2bf(float f) {
  unsigned u = __builtin_bit_cast(unsigned, f);
  u = u + 0x7FFFu + ((u >> 16) & 1u);
  return (u16)(u >> 16);
}

// Swizzled kt element index for (d, r), r in [0,32).
// XOR of the r-block (8 rows) with d-bits that VARY PER LANE on the write side
// cuts the write conflict from 16-way to 4-way; reads of 8 consecutive r stay
// contiguous (b128, 16B-aligned since LDT*2=80, swz*16).
__device__ __forceinline__ int kt_idx(int d, int r) {
  return d * LDT + ((((r >> 3) ^ ((d >> 2) & 3))) << 3) + (r & 7);
}

// b128 read of kt[col][lg*8 .. lg*8+7]
__device__ __forceinline__ v8bf kt_frag(const u16* ktb, int col, int lg) {
  return *(const v8bf*)&ktb[col * LDT + (((lg ^ ((col >> 2) & 3))) << 3)];
}

// Coalesced chunk load: thread holds, for i=0..3, floats (i*1024 + tid*4 ..+3)
// = row r=i*8+(tid>>5), cols d0..d0+3 with d0=(tid&31)*4. 4 fvec4, 4B lane
// stride per instruction -> fully coalesced, all 4 loads in flight.
__device__ __forceinline__ void load_chunk(const float* __restrict__ Kbase,
                                           int tid, fvec4* pf) {
#pragma unroll
  for (int i = 0; i < 4; ++i)
    pf[i] = *(const fvec4*)(Kbase + i * 1024 + tid * 4);
}

__device__ __forceinline__ void write_kt(const fvec4* pf, u16* ktb, int tid) {
  const int d0 = (tid & 31) * 4;
  const int rb = tid >> 5;
#pragma unroll
  for (int i = 0; i < 4; ++i) {
    const int r = i * 8 + rb;
    fvec4 v = pf[i];
    ktb[kt_idx(d0 + 0, r)] = f2bf(v[0]);
    ktb[kt_idx(d0 + 1, r)] = f2bf(v[1]);
    ktb[kt_idx(d0 + 2, r)] = f2bf(v[2]);
    ktb[kt_idx(d0 + 3, r)] = f2bf(v[3]);
  }
}

__device__ __forceinline__ void write_stage(const fvec4* pf, u16* ksb, u16* ktb,
                                            int tid) {
  const int d0 = (tid & 31) * 4;
  const int rb = tid >> 5;
#pragma unroll
  for (int i = 0; i < 4; ++i) {
    const int r = i * 8 + rb;
    fvec4 v = pf[i];
    u16 h0 = f2bf(v[0]), h1 = f2bf(v[1]), h2 = f2bf(v[2]), h3 = f2bf(v[3]);
    u16x4 u = {h0, h1, h2, h3};
    *(u16x4*)&ksb[r * LDK + d0] = u;
    ktb[kt_idx(d0 + 0, r)] = h0;
    ktb[kt_idx(d0 + 1, r)] = h1;
    ktb[kt_idx(d0 + 2, r)] = h2;
    ktb[kt_idx(d0 + 3, r)] = h3;
  }
}

// ---------------- Kernel 1: projected queries (+ fused KtK partial) --------
// grid (16 row-tiles, 8 batches), 256 threads / 4 waves.
__global__ __launch_bounds__(256) void k_proj(
    const float* __restrict__ Q, const float* __restrict__ K,
    const float* __restrict__ carry, float* __restrict__ out,
    float* __restrict__ ws, int do_syrk) {
  const int t = blockIdx.x;
  const int b = blockIdx.y;
  const int tid = threadIdx.x;
  const int w = tid >> 6;
  const int l = tid & 63;
  const int lr = l & 15;
  const int lg = l >> 4;
  const int wr = (w & 1) * 16;   // wave row offset in 32-row tile
  const int wc = (w >> 1) * 64;  // wave col offset in D
  const int r0 = t * 32;

  __shared__ u16 ks[2][32 * LDK];   // row-major K chunk (S-step B operand)
  __shared__ u16 kt[2][128 * LDT];  // transposed K chunk (PV B operand)
  __shared__ u16 sl[32 * 40];       // masked S chunk (bf16)

  const float* Kb0 = K + (size_t)(b * C_) * D_;

  // issue chunk-0 staging loads early
  fvec4 pf[4];
  load_chunk(Kb0, tid, pf);

  // --- Q A-fragments: rows r0+wr+lr, k = kk*32 + lg*8 + e
  v8bf qf[4];
  {
    const float* qrow = Q + (size_t)(b * C_ + r0 + wr + lr) * D_;
#pragma unroll
    for (int kk = 0; kk < 4; ++kk) {
      const float* p = qrow + kk * 32 + lg * 8;
      fvec4 a = *(const fvec4*)p;
      fvec4 c = *(const fvec4*)(p + 4);
      u16x4 u0 = {f2bf(a[0]), f2bf(a[1]), f2bf(a[2]), f2bf(a[3])};
      u16x4 u1 = {f2bf(c[0]), f2bf(c[1]), f2bf(c[2]), f2bf(c[3])};
      u16 tmp[8] = {u0[0], u0[1], u0[2], u0[3], u1[0], u1[1], u1[2], u1[3]};
      qf[kk] = *(const v8bf*)tmp;
    }
  }

  // --- init O with carry term: O[r][i] = sum_j Q[r][j] * carry[i][j]
  v4f acc[4] = {{0.f, 0.f, 0.f, 0.f}, {0.f, 0.f, 0.f, 0.f},
                {0.f, 0.f, 0.f, 0.f}, {0.f, 0.f, 0.f, 0.f}};
#pragma unroll
  for (int kk = 0; kk < 4; ++kk) {
#pragma unroll
    for (int n = 0; n < 4; ++n) {
      const int icol = wc + n * 16 + lr;
      const float* p = carry + (size_t)icol * D_ + kk * 32 + lg * 8;
      fvec4 a = *(const fvec4*)p;
      fvec4 c = *(const fvec4*)(p + 4);
      u16 tmp[8] = {f2bf(a[0]), f2bf(a[1]), f2bf(a[2]), f2bf(a[3]),
                    f2bf(c[0]), f2bf(c[1]), f2bf(c[2]), f2bf(c[3])};
      acc[n] = __builtin_amdgcn_mfma_f32_16x16x32_bf16(
          qf[kk], *(const v8bf*)tmp, acc[n], 0, 0, 0);
    }
  }

  // prologue: stage chunk 0
  write_stage(pf, ks[0], kt[0], tid);
  __syncthreads();

  int cur = 0;
  const int sc0 = (w >> 1) * 16;
  for (int cc = 0; cc <= t; ++cc) {
    const bool more = (cc < t);
    fvec4 nf[4];
    if (more) load_chunk(Kb0 + (size_t)(cc + 1) * 32 * D_, tid, nf);

    // S tile = Q * Kchunk^T : wave computes S[wr..+16][sc0..+16]
    v4f sacc = {0.f, 0.f, 0.f, 0.f};
#pragma unroll
    for (int kk = 0; kk < 4; ++kk) {
      v8bf bf = *(const v8bf*)&ks[cur][(sc0 + lr) * LDK + kk * 32 + lg * 8];
      sacc = __builtin_amdgcn_mfma_f32_16x16x32_bf16(qf[kk], bf, sacc, 0, 0, 0);
    }
    // masked bf16 write of S to LDS (causal on the diagonal chunk)
    const bool diag = (cc == t);
#pragma unroll
    for (int j = 0; j < 4; ++j) {
      const int sr = wr + lg * 4 + j;
      const int sc = sc0 + lr;
      float v = sacc[j];
      if (diag && sc > sr) v = 0.f;
      sl[sr * 40 + sc] = f2bf(v);
    }
    __syncthreads();

    // PV: O += S * Kchunk
    v8bf af = *(const v8bf*)&sl[(wr + lr) * 40 + lg * 8];
#pragma unroll
    for (int n = 0; n < 4; ++n) {
      v8bf bf = kt_frag(kt[cur], wc + n * 16 + lr, lg);
      acc[n] = __builtin_amdgcn_mfma_f32_16x16x32_bf16(af, bf, acc[n], 0, 0, 0);
    }
    // stage next chunk into the other buffer (readers of it synced below)
    if (more) {
      write_stage(nf, ks[cur ^ 1], kt[cur ^ 1], tid);
      cur ^= 1;
    }
    __syncthreads();
  }

  // --- out write: C/D layout col = lane&15, row = 4*(lane>>4)+j
#pragma unroll
  for (int n = 0; n < 4; ++n)
#pragma unroll
    for (int j = 0; j < 4; ++j)
      out[(size_t)(b * C_ + r0 + wr + lg * 4 + j) * D_ + wc + n * 16 + lr] =
          acc[n][j];

  // --- fused KtK partial for this block's own chunk t (still in kt[cur])
  if (do_syrk) {
    v8bf fr[8];
#pragma unroll
    for (int x = 0; x < 8; ++x) fr[x] = kt_frag(kt[cur], x * 16 + lr, lg);
    v4f a2[2][8];
#pragma unroll
    for (int mi = 0; mi < 2; ++mi)
#pragma unroll
      for (int n = 0; n < 8; ++n) {
        v4f z = {0.f, 0.f, 0.f, 0.f};
        a2[mi][n] = __builtin_amdgcn_mfma_f32_16x16x32_bf16(fr[2 * w + mi],
                                                            fr[n], z, 0, 0, 0);
      }
    float* wp = ws + (size_t)(b * 16 + t) * 16384;
#pragma unroll
    for (int mi = 0; mi < 2; ++mi)
#pragma unroll
      for (int n = 0; n < 8; ++n)
#pragma unroll
        for (int j = 0; j < 4; ++j)
          wp[(size_t)(16 * (2 * w + mi) + 4 * lg + j) * 128 + 16 * n + lr] =
              a2[mi][n][j];
  }
}

// ---------------- reduce 128 partials + carry ----------------
__global__ __launch_bounds__(256) void k_reduce128(
    const float* __restrict__ ws, const float* __restrict__ carry,
    float* __restrict__ out2) {
  const int i = blockIdx.x * 256 + threadIdx.x;
  float s = 0.f;
#pragma unroll 8
  for (int p = 0; p < 128; ++p) s += ws[(size_t)p * 16384 + i];
  out2[i] = carry[i] + 0.125f * s;
}

// ---------------- fallback: per-batch syrk (needs only 512 KiB ws) --------
__global__ __launch_bounds__(256) void k_syrk(const float* __restrict__ K,
                                              float* __restrict__ ws) {
  const int b = blockIdx.x;
  const int tid = threadIdx.x;
  const int w = tid >> 6;
  const int l = tid & 63;
  const int lr = l & 15;
  const int lg = l >> 4;

  __shared__ u16 kt[2][128 * LDT];

  v4f acc[2][8];
#pragma unroll
  for (int mi = 0; mi < 2; ++mi)
#pragma unroll
    for (int n = 0; n < 8; ++n) acc[mi][n] = (v4f){0.f, 0.f, 0.f, 0.f};

  const float* Kb = K + (size_t)(b * C_) * D_;
  fvec4 pf[4];
  load_chunk(Kb, tid, pf);
  write_kt(pf, kt[0], tid);
  __syncthreads();

  int cur = 0;
  for (int cc = 0; cc < 16; ++cc) {
    const bool more = (cc < 15);
    fvec4 nf[4];
    if (more) load_chunk(Kb + (size_t)(cc + 1) * 32 * D_, tid, nf);
    v8bf fr[8];
#pragma unroll
    for (int x = 0; x < 8; ++x) fr[x] = kt_frag(kt[cur], x * 16 + lr, lg);
#pragma unroll
    for (int mi = 0; mi < 2; ++mi)
#pragma unroll
      for (int n = 0; n < 8; ++n)
        acc[mi][n] = __builtin_amdgcn_mfma_f32_16x16x32_bf16(
            fr[2 * w + mi], fr[n], acc[mi][n], 0, 0, 0);
    if (more) {
      write_kt(nf, kt[cur ^ 1], tid);
      cur ^= 1;
    }
    __syncthreads();
  }
#pragma unroll
  for (int mi = 0; mi < 2; ++mi)
#pragma unroll
    for (int n = 0; n < 8; ++n)
#pragma unroll
      for (int j = 0; j < 4; ++j)
        ws[(size_t)b * 16384 +
           (size_t)(16 * (2 * w + mi) + 4 * lg + j) * 128 + 16 * n + lr] =
            acc[mi][n][j];
}

__global__ __launch_bounds__(256) void k_reduce8(const float* __restrict__ ws,
                                                 const float* __restrict__ carry,
                                                 float* __restrict__ out2) {
  const int i = blockIdx.x * 256 + threadIdx.x;
  float s = 0.f;
#pragma unroll
  for (int p = 0; p < 8; ++p) s += ws[(size_t)p * 16384 + i];
  out2[i] = carry[i] + 0.125f * s;
}

// ---------------- last-resort: single-block direct (no ws needed) ---------
__global__ __launch_bounds__(256) void k_syrk_direct(
    const float* __restrict__ K, const float* __restrict__ carry,
    float* __restrict__ out2) {
  const int tid = threadIdx.x;
  const int w = tid >> 6;
  const int l = tid & 63;
  const int lr = l & 15;
  const int lg = l >> 4;
  __shared__ u16 kt[2][128 * LDT];

  v4f acc[2][8];
#pragma unroll
  for (int mi = 0; mi < 2; ++mi)
#pragma unroll
    for (int n = 0; n < 8; ++n) acc[mi][n] = (v4f){0.f, 0.f, 0.f, 0.f};

  fvec4 pf[4];
  load_chunk(K, tid, pf);
  write_kt(pf, kt[0], tid);
  __syncthreads();
  int cur = 0;
  for (int g = 0; g < 128; ++g) {
    const bool more = (g < 127);
    fvec4 nf[4];
    if (more) load_chunk(K + (size_t)(g + 1) * 32 * D_, tid, nf);
    v8bf fr[8];
#pragma unroll
    for (int x = 0; x < 8; ++x) fr[x] = kt_frag(kt[cur], x * 16 + lr, lg);
#pragma unroll
    for (int mi = 0; mi < 2; ++mi)
#pragma unroll
      for (int n = 0; n < 8; ++n)
        acc[mi][n] = __builtin_amdgcn_mfma_f32_16x16x32_bf16(
            fr[2 * w + mi], fr[n], acc[mi][n], 0, 0, 0);
    if (more) {
      write_kt(nf, kt[cur ^ 1], tid);
      cur ^= 1;
    }
    __syncthreads();
  }
#pragma unroll
  for (int mi = 0; mi < 2; ++mi)
#pragma unroll
    for (int n = 0; n < 8; ++n)
#pragma unroll
      for (int j = 0; j < 4; ++j) {
        const int idx = (16 * (2 * w + mi) + 4 * lg + j) * 128 + 16 * n + lr;
        out2[idx] = carry[idx] + 0.125f * acc[mi][n][j];
      }
}

extern "C" void kernel_launch(void* const* d_in, const int* in_sizes, int n_in,
                              void* d_out, int out_size, void* d_ws,
                              size_t ws_size, hipStream_t stream) {
  const float* Q = (const float*)d_in[0];
  const float* K = (const float*)d_in[1];
  const float* carry = (const float*)d_in[2];
  float* out = (float*)d_out;
  float* out2 = out + (size_t)B_ * C_ * D_;

  const size_t need_full = (size_t)128 * 16384 * sizeof(float);  // 8 MiB
  const size_t need_small = (size_t)8 * 16384 * sizeof(float);   // 512 KiB
  const int do_syrk = (ws_size >= need_full) ? 1 : 0;

  k_proj<<<dim3(16, 8), 256, 0, stream>>>(Q, K, carry, out, (float*)d_ws,
                                          do_syrk);

  if (do_syrk) {
    k_reduce128<<<64, 256, 0, stream>>>((const float*)d_ws, carry, out2);
  } else if (ws_size >= need_small) {
    k_syrk<<<B_, 256, 0, stream>>>(K, (float*)d_ws);
    k_reduce8<<<64, 256, 0, stream>>>((const float*)d_ws, carry, out2);
  } else {
    k_syrk_direct<<<1, 256, 0, stream>>>(K, carry, out2);
  }
}

// Round 3
// 33.431 us; speedup vs baseline: 4.1689x; 1.2017x over previous
//
#include <hip/hip_runtime.h>

#define B_ 8
#define C_ 512
#define D_ 128
#define LDK 136   // ks row stride (u16)
#define LDT 40    // kt row stride (u16)

typedef __bf16 v8bf __attribute__((ext_vector_type(8)));
typedef float v4f __attribute__((ext_vector_type(4)));
typedef float fvec4 __attribute__((ext_vector_type(4)));
typedef unsigned short u16;
typedef u16 u16x4 __attribute__((ext_vector_type(4)));

// f32 -> bf16 round-to-nearest-even
__device__ __forceinline__ u16 f2bf(float f) {
  unsigned u = __builtin_bit_cast(unsigned, f);
  u = u + 0x7FFFu + ((u >> 16) & 1u);
  return (u16)(u >> 16);
}

__device__ __forceinline__ int kt_idx(int d, int r) {
  return d * LDT + ((((r >> 3) ^ ((d >> 2) & 3))) << 3) + (r & 7);
}
__device__ __forceinline__ v8bf kt_frag(const u16* ktb, int col, int lg) {
  return *(const v8bf*)&ktb[col * LDT + (((lg ^ ((col >> 2) & 3))) << 3)];
}

__device__ __forceinline__ void load_chunk(const float* __restrict__ Kbase,
                                           int tid, fvec4* pf) {
#pragma unroll
  for (int i = 0; i < 4; ++i)
    pf[i] = *(const fvec4*)(Kbase + i * 1024 + tid * 4);
}

__device__ __forceinline__ void write_stage(const fvec4* pf, u16* ksb, u16* ktb,
                                            int tid) {
  const int d0 = (tid & 31) * 4;
  const int rb = tid >> 5;
#pragma unroll
  for (int i = 0; i < 4; ++i) {
    const int r = i * 8 + rb;
    fvec4 v = pf[i];
    u16 h0 = f2bf(v[0]), h1 = f2bf(v[1]), h2 = f2bf(v[2]), h3 = f2bf(v[3]);
    u16x4 u = {h0, h1, h2, h3};
    *(u16x4*)&ksb[r * LDK + d0] = u;
    ktb[kt_idx(d0 + 0, r)] = h0;
    ktb[kt_idx(d0 + 1, r)] = h1;
    ktb[kt_idx(d0 + 2, r)] = h2;
    ktb[kt_idx(d0 + 3, r)] = h3;
  }
}

// ================= K1: per-chunk Gram G[b][t] = K_t^T K_t (f32) ============
// grid (16,8), 256 thr. Register-fragment only: no LDS, no barriers.
// frag fr[n][e] = bf16(K[chunk_row 8lg+e][16n+lr]); A-frag(m) == fr[2w+m].
__global__ __launch_bounds__(256) void k_gram(const float* __restrict__ K,
                                              float* __restrict__ G) {
  const int t = blockIdx.x, b = blockIdx.y;
  const int tid = threadIdx.x;
  const int w = tid >> 6, l = tid & 63, lr = l & 15, lg = l >> 4;
  const float* Kc = K + (size_t)(b * C_ + t * 32) * D_;

  v8bf fr[8];
#pragma unroll
  for (int n = 0; n < 8; ++n) {
    u16 tmp[8];
#pragma unroll
    for (int e = 0; e < 8; ++e)
      tmp[e] = f2bf(Kc[(size_t)(8 * lg + e) * D_ + 16 * n + lr]);
    fr[n] = *(const v8bf*)tmp;
  }
  float* Gp = G + (size_t)(b * 16 + t) * 16384;
#pragma unroll
  for (int mi = 0; mi < 2; ++mi) {
    v8bf am = fr[2 * w + mi];
#pragma unroll
    for (int n = 0; n < 8; ++n) {
      v4f z = {0.f, 0.f, 0.f, 0.f};
      v4f a = __builtin_amdgcn_mfma_f32_16x16x32_bf16(am, fr[n], z, 0, 0, 0);
#pragma unroll
      for (int j = 0; j < 4; ++j)
        Gp[(size_t)(32 * w + 16 * mi + 4 * lg + j) * 128 + 16 * n + lr] = a[j];
    }
  }
}

// ====== K2: in-place exclusive prefix  G[b][t] -> M'[b][t]=carry+prefix ====
// also emits out2 = carry + mean_b(sum_t G). grid 64, 256 thr.
__global__ __launch_bounds__(256) void k_prefix(float* __restrict__ G,
                                                const float* __restrict__ carry,
                                                float* __restrict__ out2) {
  const int e = blockIdx.x * 256 + threadIdx.x;  // 0..16383
  const float c = carry[e];
  float tot = 0.f;
  for (int b = 0; b < B_; ++b) {
    float* gb = G + (size_t)b * 16 * 16384 + e;
    float run = 0.f;
#pragma unroll
    for (int t = 0; t < 16; ++t) {
      float g = gb[(size_t)t * 16384];
      gb[(size_t)t * 16384] = c + run;  // exclusive prefix + carry
      run += g;
    }
    tot += run;
  }
  out2[e] = c + 0.125f * tot;
}

// ============ K3: out = Q * M'^T  +  intra-chunk causal S*K ================
// grid (16,8), 256 thr / 4 waves. Exactly ONE staged chunk per block.
__global__ __launch_bounds__(256) void k_out(const float* __restrict__ Q,
                                             const float* __restrict__ K,
                                             const float* __restrict__ Mp,
                                             float* __restrict__ out) {
  const int t = blockIdx.x, b = blockIdx.y;
  const int tid = threadIdx.x;
  const int w = tid >> 6, l = tid & 63, lr = l & 15, lg = l >> 4;
  const int wr = (w & 1) * 16, wc = (w >> 1) * 64;
  const int r0 = t * 32;

  __shared__ u16 ks[32 * LDK];
  __shared__ u16 kt[128 * LDT];
  __shared__ u16 sl[32 * 40];

  // issue K-chunk staging loads first
  fvec4 pf[4];
  load_chunk(K + (size_t)(b * C_ + r0) * D_, tid, pf);

  // Q A-fragments: rows r0+wr+lr, k = kk*32 + lg*8 + e
  v8bf qf[4];
  {
    const float* qrow = Q + (size_t)(b * C_ + r0 + wr + lr) * D_;
#pragma unroll
    for (int kk = 0; kk < 4; ++kk) {
      const float* p = qrow + kk * 32 + lg * 8;
      fvec4 a = *(const fvec4*)p;
      fvec4 c2 = *(const fvec4*)(p + 4);
      u16 tmp[8] = {f2bf(a[0]),  f2bf(a[1]),  f2bf(a[2]),  f2bf(a[3]),
                    f2bf(c2[0]), f2bf(c2[1]), f2bf(c2[2]), f2bf(c2[3])};
      qf[kk] = *(const v8bf*)tmp;
    }
  }

  write_stage(pf, ks, kt, tid);

  // acc = Q * M'^T  (M' rows are contiguous: dwordx4 loads, no transpose)
  v4f acc[4] = {{0.f, 0.f, 0.f, 0.f}, {0.f, 0.f, 0.f, 0.f},
                {0.f, 0.f, 0.f, 0.f}, {0.f, 0.f, 0.f, 0.f}};
  {
    const float* mp = Mp + (size_t)(b * 16 + t) * 16384;
#pragma unroll
    for (int kk = 0; kk < 4; ++kk) {
#pragma unroll
      for (int n = 0; n < 4; ++n) {
        const float* p = mp + (size_t)(wc + 16 * n + lr) * 128 + 32 * kk + 8 * lg;
        fvec4 a = *(const fvec4*)p;
        fvec4 c2 = *(const fvec4*)(p + 4);
        u16 tmp[8] = {f2bf(a[0]),  f2bf(a[1]),  f2bf(a[2]),  f2bf(a[3]),
                      f2bf(c2[0]), f2bf(c2[1]), f2bf(c2[2]), f2bf(c2[3])};
        acc[n] = __builtin_amdgcn_mfma_f32_16x16x32_bf16(
            qf[kk], *(const v8bf*)tmp, acc[n], 0, 0, 0);
      }
    }
  }
  __syncthreads();

  // S tile = Q * Kchunk^T (diagonal chunk, causal mask always)
  const int sc0 = (w >> 1) * 16;
  v4f sacc = {0.f, 0.f, 0.f, 0.f};
#pragma unroll
  for (int kk = 0; kk < 4; ++kk) {
    v8bf bf = *(const v8bf*)&ks[(sc0 + lr) * LDK + kk * 32 + lg * 8];
    sacc = __builtin_amdgcn_mfma_f32_16x16x32_bf16(qf[kk], bf, sacc, 0, 0, 0);
  }
#pragma unroll
  for (int j = 0; j < 4; ++j) {
    const int sr = wr + lg * 4 + j;
    const int sc = sc0 + lr;
    float v = sacc[j];
    if (sc > sr) v = 0.f;
    sl[sr * 40 + sc] = f2bf(v);
  }
  __syncthreads();

  // PV: acc += S * Kchunk
  v8bf af = *(const v8bf*)&sl[(wr + lr) * 40 + lg * 8];
#pragma unroll
  for (int n = 0; n < 4; ++n) {
    v8bf bf = kt_frag(kt, wc + n * 16 + lr, lg);
    acc[n] = __builtin_amdgcn_mfma_f32_16x16x32_bf16(af, bf, acc[n], 0, 0, 0);
  }

  // epilogue: C/D layout col = lane&15, row = 4*(lane>>4)+j
#pragma unroll
  for (int n = 0; n < 4; ++n)
#pragma unroll
    for (int j = 0; j < 4; ++j)
      out[(size_t)(b * C_ + r0 + wr + lg * 4 + j) * D_ + wc + n * 16 + lr] =
          acc[n][j];
}

// ================= fallback (ws too small): round-2 monolith ===============
__global__ __launch_bounds__(256) void k_proj_fb(
    const float* __restrict__ Q, const float* __restrict__ K,
    const float* __restrict__ carry, float* __restrict__ out) {
  const int t = blockIdx.x, b = blockIdx.y;
  const int tid = threadIdx.x;
  const int w = tid >> 6, l = tid & 63, lr = l & 15, lg = l >> 4;
  const int wr = (w & 1) * 16, wc = (w >> 1) * 64;
  const int r0 = t * 32;

  __shared__ u16 ks[2][32 * LDK];
  __shared__ u16 kt[2][128 * LDT];
  __shared__ u16 sl[32 * 40];

  const float* Kb0 = K + (size_t)(b * C_) * D_;
  fvec4 pf[4];
  load_chunk(Kb0, tid, pf);

  v8bf qf[4];
  {
    const float* qrow = Q + (size_t)(b * C_ + r0 + wr + lr) * D_;
#pragma unroll
    for (int kk = 0; kk < 4; ++kk) {
      const float* p = qrow + kk * 32 + lg * 8;
      fvec4 a = *(const fvec4*)p;
      fvec4 c2 = *(const fvec4*)(p + 4);
      u16 tmp[8] = {f2bf(a[0]),  f2bf(a[1]),  f2bf(a[2]),  f2bf(a[3]),
                    f2bf(c2[0]), f2bf(c2[1]), f2bf(c2[2]), f2bf(c2[3])};
      qf[kk] = *(const v8bf*)tmp;
    }
  }

  v4f acc[4] = {{0.f, 0.f, 0.f, 0.f}, {0.f, 0.f, 0.f, 0.f},
                {0.f, 0.f, 0.f, 0.f}, {0.f, 0.f, 0.f, 0.f}};
#pragma unroll
  for (int kk = 0; kk < 4; ++kk) {
#pragma unroll
    for (int n = 0; n < 4; ++n) {
      const float* p = carry + (size_t)(wc + n * 16 + lr) * D_ + kk * 32 + lg * 8;
      fvec4 a = *(const fvec4*)p;
      fvec4 c2 = *(const fvec4*)(p + 4);
      u16 tmp[8] = {f2bf(a[0]),  f2bf(a[1]),  f2bf(a[2]),  f2bf(a[3]),
                    f2bf(c2[0]), f2bf(c2[1]), f2bf(c2[2]), f2bf(c2[3])};
      acc[n] = __builtin_amdgcn_mfma_f32_16x16x32_bf16(
          qf[kk], *(const v8bf*)tmp, acc[n], 0, 0, 0);
    }
  }

  write_stage(pf, ks[0], kt[0], tid);
  __syncthreads();

  int cur = 0;
  const int sc0 = (w >> 1) * 16;
  for (int cc = 0; cc <= t; ++cc) {
    const bool more = (cc < t);
    fvec4 nf[4];
    if (more) load_chunk(Kb0 + (size_t)(cc + 1) * 32 * D_, tid, nf);

    v4f sacc = {0.f, 0.f, 0.f, 0.f};
#pragma unroll
    for (int kk = 0; kk < 4; ++kk) {
      v8bf bf = *(const v8bf*)&ks[cur][(sc0 + lr) * LDK + kk * 32 + lg * 8];
      sacc = __builtin_amdgcn_mfma_f32_16x16x32_bf16(qf[kk], bf, sacc, 0, 0, 0);
    }
    const bool diag = (cc == t);
#pragma unroll
    for (int j = 0; j < 4; ++j) {
      const int sr = wr + lg * 4 + j;
      const int sc = sc0 + lr;
      float v = sacc[j];
      if (diag && sc > sr) v = 0.f;
      sl[sr * 40 + sc] = f2bf(v);
    }
    __syncthreads();

    v8bf af = *(const v8bf*)&sl[(wr + lr) * 40 + lg * 8];
#pragma unroll
    for (int n = 0; n < 4; ++n) {
      v8bf bf = kt_frag(kt[cur], wc + n * 16 + lr, lg);
      acc[n] = __builtin_amdgcn_mfma_f32_16x16x32_bf16(af, bf, acc[n], 0, 0, 0);
    }
    if (more) {
      write_stage(nf, ks[cur ^ 1], kt[cur ^ 1], tid);
      cur ^= 1;
    }
    __syncthreads();
  }

#pragma unroll
  for (int n = 0; n < 4; ++n)
#pragma unroll
    for (int j = 0; j < 4; ++j)
      out[(size_t)(b * C_ + r0 + wr + lg * 4 + j) * D_ + wc + n * 16 + lr] =
          acc[n][j];
}

__global__ __launch_bounds__(256) void k_syrk_direct(
    const float* __restrict__ K, const float* __restrict__ carry,
    float* __restrict__ out2) {
  const int tid = threadIdx.x;
  const int w = tid >> 6, l = tid & 63, lr = l & 15, lg = l >> 4;
  __shared__ u16 kt[2][128 * LDT];

  v4f acc[2][8];
#pragma unroll
  for (int mi = 0; mi < 2; ++mi)
#pragma unroll
    for (int n = 0; n < 8; ++n) acc[mi][n] = (v4f){0.f, 0.f, 0.f, 0.f};

  fvec4 pf[4];
  load_chunk(K, tid, pf);
  {
    const int d0 = (tid & 31) * 4;
    const int rb = tid >> 5;
#pragma unroll
    for (int i = 0; i < 4; ++i) {
      const int r = i * 8 + rb;
      fvec4 v = pf[i];
      kt[0][kt_idx(d0 + 0, r)] = f2bf(v[0]);
      kt[0][kt_idx(d0 + 1, r)] = f2bf(v[1]);
      kt[0][kt_idx(d0 + 2, r)] = f2bf(v[2]);
      kt[0][kt_idx(d0 + 3, r)] = f2bf(v[3]);
    }
  }
  __syncthreads();
  int cur = 0;
  for (int g = 0; g < 128; ++g) {
    const bool more = (g < 127);
    fvec4 nf[4];
    if (more) load_chunk(K + (size_t)(g + 1) * 32 * D_, tid, nf);
    v8bf fr[8];
#pragma unroll
    for (int x = 0; x < 8; ++x) fr[x] = kt_frag(kt[cur], x * 16 + lr, lg);
#pragma unroll
    for (int mi = 0; mi < 2; ++mi)
#pragma unroll
      for (int n = 0; n < 8; ++n)
        acc[mi][n] = __builtin_amdgcn_mfma_f32_16x16x32_bf16(
            fr[2 * w + mi], fr[n], acc[mi][n], 0, 0, 0);
    if (more) {
      const int d0 = (tid & 31) * 4;
      const int rb = tid >> 5;
      u16* kb = kt[cur ^ 1];
#pragma unroll
      for (int i = 0; i < 4; ++i) {
        const int r = i * 8 + rb;
        fvec4 v = nf[i];
        kb[kt_idx(d0 + 0, r)] = f2bf(v[0]);
        kb[kt_idx(d0 + 1, r)] = f2bf(v[1]);
        kb[kt_idx(d0 + 2, r)] = f2bf(v[2]);
        kb[kt_idx(d0 + 3, r)] = f2bf(v[3]);
      }
      cur ^= 1;
    }
    __syncthreads();
  }
#pragma unroll
  for (int mi = 0; mi < 2; ++mi)
#pragma unroll
    for (int n = 0; n < 8; ++n)
#pragma unroll
      for (int j = 0; j < 4; ++j) {
        const int idx = (16 * (2 * w + mi) + 4 * lg + j) * 128 + 16 * n + lr;
        out2[idx] = carry[idx] + 0.125f * acc[mi][n][j];
      }
}

extern "C" void kernel_launch(void* const* d_in, const int* in_sizes, int n_in,
                              void* d_out, int out_size, void* d_ws,
                              size_t ws_size, hipStream_t stream) {
  const float* Q = (const float*)d_in[0];
  const float* K = (const float*)d_in[1];
  const float* carry = (const float*)d_in[2];
  float* out = (float*)d_out;
  float* out2 = out + (size_t)B_ * C_ * D_;

  const size_t need = (size_t)128 * 16384 * sizeof(float);  // 8 MiB

  if (ws_size >= need) {
    float* G = (float*)d_ws;  // becomes M' in-place after k_prefix
    k_gram<<<dim3(16, 8), 256, 0, stream>>>(K, G);
    k_prefix<<<64, 256, 0, stream>>>(G, carry, out2);
    k_out<<<dim3(16, 8), 256, 0, stream>>>(Q, K, G, out);
  } else {
    k_proj_fb<<<dim3(16, 8), 256, 0, stream>>>(Q, K, carry, out);
    k_syrk_direct<<<1, 256, 0, stream>>>(K, carry, out2);
  }
}

// Round 4
// 27.845 us; speedup vs baseline: 5.0053x; 1.2006x over previous
//
#include <hip/hip_runtime.h>

#define B_ 8
#define C_ 512
#define D_ 128
#define LDK 136   // fallback ks row stride (u16)
#define LDT 40    // fallback kt row stride (u16)

typedef __bf16 v8bf __attribute__((ext_vector_type(8)));
typedef float v4f __attribute__((ext_vector_type(4)));
typedef float fvec4 __attribute__((ext_vector_type(4)));
typedef unsigned short u16;
typedef u16 u16x4 __attribute__((ext_vector_type(4)));

// f32 -> bf16 round-to-nearest-even
__device__ __forceinline__ u16 f2bf(float f) {
  unsigned u = __builtin_bit_cast(unsigned, f);
  u = u + 0x7FFFu + ((u >> 16) & 1u);
  return (u16)(u >> 16);
}

// ================= K1: per-chunk Gram G[b][t] = K_t^T K_t (f32) ============
// grid (16,8), 256 thr. Register fragments only: no LDS, no barriers.
__global__ __launch_bounds__(256) void k_gram(const float* __restrict__ K,
                                              float* __restrict__ G) {
  const int t = blockIdx.x, b = blockIdx.y;
  const int tid = threadIdx.x;
  const int w = tid >> 6, l = tid & 63, lr = l & 15, lg = l >> 4;
  const float* Kc = K + (size_t)(b * C_ + t * 32) * D_;

  v8bf fr[8];
#pragma unroll
  for (int n = 0; n < 8; ++n) {
    u16 tmp[8];
#pragma unroll
    for (int e = 0; e < 8; ++e)
      tmp[e] = f2bf(Kc[(size_t)(8 * lg + e) * D_ + 16 * n + lr]);
    fr[n] = *(const v8bf*)tmp;
  }
  float* Gp = G + (size_t)(b * 16 + t) * 16384;
#pragma unroll
  for (int mi = 0; mi < 2; ++mi) {
    v8bf am = fr[2 * w + mi];
#pragma unroll
    for (int n = 0; n < 8; ++n) {
      v4f z = {0.f, 0.f, 0.f, 0.f};
      v4f a = __builtin_amdgcn_mfma_f32_16x16x32_bf16(am, fr[n], z, 0, 0, 0);
#pragma unroll
      for (int j = 0; j < 4; ++j)
        Gp[(size_t)(32 * w + 16 * mi + 4 * lg + j) * 128 + 16 * n + lr] = a[j];
    }
  }
}

// ====== K2: exclusive prefix -> M' (bf16) + per-batch totals (f32) =========
// grid (64,8) = 512 blocks. M'[b][t][e] = bf16(carry[e] + sum_{t'<t} G).
__global__ __launch_bounds__(256) void k_prefix(const float* __restrict__ G,
                                                const float* __restrict__ carry,
                                                u16* __restrict__ Mp,
                                                float* __restrict__ tot) {
  const int b = blockIdx.y;
  const int e = blockIdx.x * 256 + threadIdx.x;  // 0..16383
  const float c = carry[e];
  const float* gb = G + (size_t)b * 16 * 16384 + e;
  u16* mb = Mp + (size_t)b * 16 * 16384 + e;
  float run = 0.f;
#pragma unroll
  for (int t = 0; t < 16; ++t) {
    float g = gb[(size_t)t * 16384];
    mb[(size_t)t * 16384] = f2bf(c + run);
    run += g;
  }
  tot[(size_t)b * 16384 + e] = run;
}

// ===== K3: out = Q*M'^T + intra-chunk causal S*K ; t==16 blocks do out2 ====
// grid (17,8), 256 thr / 4 waves. LDS only for the S hand-off.
__global__ __launch_bounds__(256) void k_out(
    const float* __restrict__ Q, const float* __restrict__ K,
    const u16* __restrict__ Mp, const float* __restrict__ tot,
    const float* __restrict__ carry, float* __restrict__ out,
    float* __restrict__ out2) {
  const int t = blockIdx.x, b = blockIdx.y;
  const int tid = threadIdx.x;

  if (t == 16) {  // out2 = carry + mean_b(tot): slice [b*2048, (b+1)*2048)
    const int e0 = b * 2048 + tid * 8;
    fvec4 s0 = {0.f, 0.f, 0.f, 0.f}, s1 = {0.f, 0.f, 0.f, 0.f};
#pragma unroll
    for (int bb = 0; bb < 8; ++bb) {
      s0 += *(const fvec4*)(tot + (size_t)bb * 16384 + e0);
      s1 += *(const fvec4*)(tot + (size_t)bb * 16384 + e0 + 4);
    }
    fvec4 c0 = *(const fvec4*)(carry + e0);
    fvec4 c1 = *(const fvec4*)(carry + e0 + 4);
    *(fvec4*)(out2 + e0) = c0 + 0.125f * s0;
    *(fvec4*)(out2 + e0 + 4) = c1 + 0.125f * s1;
    return;
  }

  const int w = tid >> 6, l = tid & 63, lr = l & 15, lg = l >> 4;
  const int wr = (w & 1) * 16, wc = (w >> 1) * 64, sc0 = (w >> 1) * 16;
  const int r0 = t * 32;

  __shared__ u16 sl[32 * 40];

  const float* Kc = K + (size_t)(b * C_ + r0) * D_;

  // PV B-frags straight from global K: pb[n][e] = bf16(Kc[8lg+e][wc+16n+lr])
  v8bf pb[4];
#pragma unroll
  for (int n = 0; n < 4; ++n) {
    u16 tmp[8];
#pragma unroll
    for (int e = 0; e < 8; ++e)
      tmp[e] = f2bf(Kc[(size_t)(8 * lg + e) * D_ + wc + 16 * n + lr]);
    pb[n] = *(const v8bf*)tmp;
  }

  // S-step B-frags: row sc0+lr of the chunk, 8 contiguous d per kk
  v8bf sb[4];
  {
    const float* krow = Kc + (size_t)(sc0 + lr) * D_;
#pragma unroll
    for (int kk = 0; kk < 4; ++kk) {
      fvec4 a = *(const fvec4*)(krow + kk * 32 + 8 * lg);
      fvec4 c2 = *(const fvec4*)(krow + kk * 32 + 8 * lg + 4);
      u16 tmp[8] = {f2bf(a[0]),  f2bf(a[1]),  f2bf(a[2]),  f2bf(a[3]),
                    f2bf(c2[0]), f2bf(c2[1]), f2bf(c2[2]), f2bf(c2[3])};
      sb[kk] = *(const v8bf*)tmp;
    }
  }

  // Q A-frags: rows r0+wr+lr, k = kk*32 + 8lg + e
  v8bf qf[4];
  {
    const float* qrow = Q + (size_t)(b * C_ + r0 + wr + lr) * D_;
#pragma unroll
    for (int kk = 0; kk < 4; ++kk) {
      const float* p = qrow + kk * 32 + 8 * lg;
      fvec4 a = *(const fvec4*)p;
      fvec4 c2 = *(const fvec4*)(p + 4);
      u16 tmp[8] = {f2bf(a[0]),  f2bf(a[1]),  f2bf(a[2]),  f2bf(a[3]),
                    f2bf(c2[0]), f2bf(c2[1]), f2bf(c2[2]), f2bf(c2[3])};
      qf[kk] = *(const v8bf*)tmp;
    }
  }

  // M' B-frags: direct bf16 b128 loads
  v8bf mf[4][4];
  {
    const u16* mp = Mp + (size_t)(b * 16 + t) * 16384;
#pragma unroll
    for (int kk = 0; kk < 4; ++kk)
#pragma unroll
      for (int n = 0; n < 4; ++n)
        mf[kk][n] =
            *(const v8bf*)(mp + (size_t)(wc + 16 * n + lr) * 128 + 32 * kk +
                           8 * lg);
  }

  // S tile = Q * Kchunk^T (diagonal chunk, causal mask)
  v4f sacc = {0.f, 0.f, 0.f, 0.f};
#pragma unroll
  for (int kk = 0; kk < 4; ++kk)
    sacc = __builtin_amdgcn_mfma_f32_16x16x32_bf16(qf[kk], sb[kk], sacc, 0, 0, 0);
#pragma unroll
  for (int j = 0; j < 4; ++j) {
    const int sr = wr + lg * 4 + j;
    const int sc = sc0 + lr;
    float v = sacc[j];
    if (sc > sr) v = 0.f;
    sl[sr * 40 + sc] = f2bf(v);
  }

  // M-term MFMAs overlap the barrier wait
  v4f acc[4] = {{0.f, 0.f, 0.f, 0.f}, {0.f, 0.f, 0.f, 0.f},
                {0.f, 0.f, 0.f, 0.f}, {0.f, 0.f, 0.f, 0.f}};
#pragma unroll
  for (int kk = 0; kk < 4; ++kk)
#pragma unroll
    for (int n = 0; n < 4; ++n)
      acc[n] = __builtin_amdgcn_mfma_f32_16x16x32_bf16(qf[kk], mf[kk][n],
                                                       acc[n], 0, 0, 0);
  __syncthreads();

  // PV: acc += S * Kchunk
  v8bf af = *(const v8bf*)&sl[(wr + lr) * 40 + lg * 8];
#pragma unroll
  for (int n = 0; n < 4; ++n)
    acc[n] = __builtin_amdgcn_mfma_f32_16x16x32_bf16(af, pb[n], acc[n], 0, 0, 0);

  // epilogue: C/D layout col = lane&15, row = 4*(lane>>4)+j
#pragma unroll
  for (int n = 0; n < 4; ++n)
#pragma unroll
    for (int j = 0; j < 4; ++j)
      out[(size_t)(b * C_ + r0 + wr + lg * 4 + j) * D_ + wc + n * 16 + lr] =
          acc[n][j];
}

// ================= fallback path (ws too small) ============================
__device__ __forceinline__ int kt_idx(int d, int r) {
  return d * LDT + ((((r >> 3) ^ ((d >> 2) & 3))) << 3) + (r & 7);
}
__device__ __forceinline__ v8bf kt_frag(const u16* ktb, int col, int lg) {
  return *(const v8bf*)&ktb[col * LDT + (((lg ^ ((col >> 2) & 3))) << 3)];
}
__device__ __forceinline__ void load_chunk(const float* __restrict__ Kbase,
                                           int tid, fvec4* pf) {
#pragma unroll
  for (int i = 0; i < 4; ++i)
    pf[i] = *(const fvec4*)(Kbase + i * 1024 + tid * 4);
}
__device__ __forceinline__ void write_stage(const fvec4* pf, u16* ksb, u16* ktb,
                                            int tid) {
  const int d0 = (tid & 31) * 4;
  const int rb = tid >> 5;
#pragma unroll
  for (int i = 0; i < 4; ++i) {
    const int r = i * 8 + rb;
    fvec4 v = pf[i];
    u16 h0 = f2bf(v[0]), h1 = f2bf(v[1]), h2 = f2bf(v[2]), h3 = f2bf(v[3]);
    u16x4 u = {h0, h1, h2, h3};
    *(u16x4*)&ksb[r * LDK + d0] = u;
    ktb[kt_idx(d0 + 0, r)] = h0;
    ktb[kt_idx(d0 + 1, r)] = h1;
    ktb[kt_idx(d0 + 2, r)] = h2;
    ktb[kt_idx(d0 + 3, r)] = h3;
  }
}

__global__ __launch_bounds__(256) void k_proj_fb(
    const float* __restrict__ Q, const float* __restrict__ K,
    const float* __restrict__ carry, float* __restrict__ out) {
  const int t = blockIdx.x, b = blockIdx.y;
  const int tid = threadIdx.x;
  const int w = tid >> 6, l = tid & 63, lr = l & 15, lg = l >> 4;
  const int wr = (w & 1) * 16, wc = (w >> 1) * 64;
  const int r0 = t * 32;

  __shared__ u16 ks[2][32 * LDK];
  __shared__ u16 kt[2][128 * LDT];
  __shared__ u16 sl[32 * 40];

  const float* Kb0 = K + (size_t)(b * C_) * D_;
  fvec4 pf[4];
  load_chunk(Kb0, tid, pf);

  v8bf qf[4];
  {
    const float* qrow = Q + (size_t)(b * C_ + r0 + wr + lr) * D_;
#pragma unroll
    for (int kk = 0; kk < 4; ++kk) {
      const float* p = qrow + kk * 32 + lg * 8;
      fvec4 a = *(const fvec4*)p;
      fvec4 c2 = *(const fvec4*)(p + 4);
      u16 tmp[8] = {f2bf(a[0]),  f2bf(a[1]),  f2bf(a[2]),  f2bf(a[3]),
                    f2bf(c2[0]), f2bf(c2[1]), f2bf(c2[2]), f2bf(c2[3])};
      qf[kk] = *(const v8bf*)tmp;
    }
  }

  v4f acc[4] = {{0.f, 0.f, 0.f, 0.f}, {0.f, 0.f, 0.f, 0.f},
                {0.f, 0.f, 0.f, 0.f}, {0.f, 0.f, 0.f, 0.f}};
#pragma unroll
  for (int kk = 0; kk < 4; ++kk) {
#pragma unroll
    for (int n = 0; n < 4; ++n) {
      const float* p =
          carry + (size_t)(wc + n * 16 + lr) * D_ + kk * 32 + lg * 8;
      fvec4 a = *(const fvec4*)p;
      fvec4 c2 = *(const fvec4*)(p + 4);
      u16 tmp[8] = {f2bf(a[0]),  f2bf(a[1]),  f2bf(a[2]),  f2bf(a[3]),
                    f2bf(c2[0]), f2bf(c2[1]), f2bf(c2[2]), f2bf(c2[3])};
      acc[n] = __builtin_amdgcn_mfma_f32_16x16x32_bf16(
          qf[kk], *(const v8bf*)tmp, acc[n], 0, 0, 0);
    }
  }

  write_stage(pf, ks[0], kt[0], tid);
  __syncthreads();

  int cur = 0;
  const int sc0 = (w >> 1) * 16;
  for (int cc = 0; cc <= t; ++cc) {
    const bool more = (cc < t);
    fvec4 nf[4];
    if (more) load_chunk(Kb0 + (size_t)(cc + 1) * 32 * D_, tid, nf);

    v4f sacc = {0.f, 0.f, 0.f, 0.f};
#pragma unroll
    for (int kk = 0; kk < 4; ++kk) {
      v8bf bf = *(const v8bf*)&ks[cur][(sc0 + lr) * LDK + kk * 32 + lg * 8];
      sacc = __builtin_amdgcn_mfma_f32_16x16x32_bf16(qf[kk], bf, sacc, 0, 0, 0);
    }
    const bool diag = (cc == t);
#pragma unroll
    for (int j = 0; j < 4; ++j) {
      const int sr = wr + lg * 4 + j;
      const int sc = sc0 + lr;
      float v = sacc[j];
      if (diag && sc > sr) v = 0.f;
      sl[sr * 40 + sc] = f2bf(v);
    }
    __syncthreads();

    v8bf af = *(const v8bf*)&sl[(wr + lr) * 40 + lg * 8];
#pragma unroll
    for (int n = 0; n < 4; ++n) {
      v8bf bf = kt_frag(kt[cur], wc + n * 16 + lr, lg);
      acc[n] = __builtin_amdgcn_mfma_f32_16x16x32_bf16(af, bf, acc[n], 0, 0, 0);
    }
    if (more) {
      write_stage(nf, ks[cur ^ 1], kt[cur ^ 1], tid);
      cur ^= 1;
    }
    __syncthreads();
  }

#pragma unroll
  for (int n = 0; n < 4; ++n)
#pragma unroll
    for (int j = 0; j < 4; ++j)
      out[(size_t)(b * C_ + r0 + wr + lg * 4 + j) * D_ + wc + n * 16 + lr] =
          acc[n][j];
}

__global__ __launch_bounds__(256) void k_syrk_direct(
    const float* __restrict__ K, const float* __restrict__ carry,
    float* __restrict__ out2) {
  const int tid = threadIdx.x;
  const int w = tid >> 6, l = tid & 63, lr = l & 15, lg = l >> 4;
  __shared__ u16 kt[2][128 * LDT];

  v4f acc[2][8];
#pragma unroll
  for (int mi = 0; mi < 2; ++mi)
#pragma unroll
    for (int n = 0; n < 8; ++n) acc[mi][n] = (v4f){0.f, 0.f, 0.f, 0.f};

  fvec4 pf[4];
  load_chunk(K, tid, pf);
  {
    const int d0 = (tid & 31) * 4;
    const int rb = tid >> 5;
#pragma unroll
    for (int i = 0; i < 4; ++i) {
      const int r = i * 8 + rb;
      fvec4 v = pf[i];
      kt[0][kt_idx(d0 + 0, r)] = f2bf(v[0]);
      kt[0][kt_idx(d0 + 1, r)] = f2bf(v[1]);
      kt[0][kt_idx(d0 + 2, r)] = f2bf(v[2]);
      kt[0][kt_idx(d0 + 3, r)] = f2bf(v[3]);
    }
  }
  __syncthreads();
  int cur = 0;
  for (int g = 0; g < 128; ++g) {
    const bool more = (g < 127);
    fvec4 nf[4];
    if (more) load_chunk(K + (size_t)(g + 1) * 32 * D_, tid, nf);
    v8bf fr[8];
#pragma unroll
    for (int x = 0; x < 8; ++x) fr[x] = kt_frag(kt[cur], x * 16 + lr, lg);
#pragma unroll
    for (int mi = 0; mi < 2; ++mi)
#pragma unroll
      for (int n = 0; n < 8; ++n)
        acc[mi][n] = __builtin_amdgcn_mfma_f32_16x16x32_bf16(
            fr[2 * w + mi], fr[n], acc[mi][n], 0, 0, 0);
    if (more) {
      const int d0 = (tid & 31) * 4;
      const int rb = tid >> 5;
      u16* kb = kt[cur ^ 1];
#pragma unroll
      for (int i = 0; i < 4; ++i) {
        const int r = i * 8 + rb;
        fvec4 v = nf[i];
        kb[kt_idx(d0 + 0, r)] = f2bf(v[0]);
        kb[kt_idx(d0 + 1, r)] = f2bf(v[1]);
        kb[kt_idx(d0 + 2, r)] = f2bf(v[2]);
        kb[kt_idx(d0 + 3, r)] = f2bf(v[3]);
      }
      cur ^= 1;
    }
    __syncthreads();
  }
#pragma unroll
  for (int mi = 0; mi < 2; ++mi)
#pragma unroll
    for (int n = 0; n < 8; ++n)
#pragma unroll
      for (int j = 0; j < 4; ++j) {
        const int idx = (16 * (2 * w + mi) + 4 * lg + j) * 128 + 16 * n + lr;
        out2[idx] = carry[idx] + 0.125f * acc[mi][n][j];
      }
}

extern "C" void kernel_launch(void* const* d_in, const int* in_sizes, int n_in,
                              void* d_out, int out_size, void* d_ws,
                              size_t ws_size, hipStream_t stream) {
  const float* Q = (const float*)d_in[0];
  const float* K = (const float*)d_in[1];
  const float* carry = (const float*)d_in[2];
  float* out = (float*)d_out;
  float* out2 = out + (size_t)B_ * C_ * D_;

  // ws layout: G f32 [128*16384] | M' u16 [128*16384] | tot f32 [8*16384]
  const size_t nG = (size_t)128 * 16384;          // floats
  const size_t nMpF = nG / 2;                     // float-equivalents for u16
  const size_t need = (nG + nMpF + (size_t)8 * 16384) * sizeof(float);

  if (ws_size >= need) {
    float* G = (float*)d_ws;
    u16* Mp = (u16*)((float*)d_ws + nG);
    float* tot = (float*)d_ws + nG + nMpF;
    k_gram<<<dim3(16, 8), 256, 0, stream>>>(K, G);
    k_prefix<<<dim3(64, 8), 256, 0, stream>>>(G, carry, Mp, tot);
    k_out<<<dim3(17, 8), 256, 0, stream>>>(Q, K, Mp, tot, carry, out, out2);
  } else {
    k_proj_fb<<<dim3(16, 8), 256, 0, stream>>>(Q, K, carry, out);
    k_syrk_direct<<<1, 256, 0, stream>>>(K, carry, out2);
  }
}